// Round 21
// baseline (1585.990 us; speedup 1.0000x reference)
//
#include <hip/hip_runtime.h>
#include <hip/hip_bf16.h>

#define SQ 1024
#define DM 768
#define NH 12
#define NL 6
#define NV 32000
#define KDH 64
#define FFD 3072

using bf16 = __hip_bfloat16;
typedef __attribute__((ext_vector_type(4))) float f32x4;
typedef __attribute__((ext_vector_type(8))) short bf16x8;

// ---------------- diagnostic fill (fp32 out) ----------------
__global__ void fill_kernel(float* __restrict__ out, long n, float val) {
  const long stride = (long)gridDim.x * blockDim.x;
  for (long i = (long)blockIdx.x * blockDim.x + threadIdx.x; i < n; i += stride)
    out[i] = val;
}

// async global->LDS, 16 bytes per lane
__device__ __forceinline__ void gload16(const void* g, void* l) {
  __builtin_amdgcn_global_load_lds(
      (const __attribute__((address_space(1))) unsigned int*)g,
      (__attribute__((address_space(3))) unsigned int*)l, 16, 0, 0);
}

// ---------------- 256x128 MFMA GEMM, 512 thr (8 waves), 3-buf, one barrier/K ----------------
// r21: BM=256 doubles compute per barrier at identical per-wave serial path;
// 2 blocks/CU x 8 waves = 16 waves/CU. LDS/buf = A 16K + B 8K = 24K; 3 bufs =
// 72K (dynamic). Stage = 3 loads/thread; waits vmcnt(3) steady, vmcnt(0) tail.
// TRI: 20 lower-triangle tiles (i in [0,4), j <= 2i+1). CTRUNC: K -> m0+256.
// QKV routing per-tile as r20 (b = grow>>10 decomposition).
// Epilogue: DIRECT stores only (r13/r14: LDS-reuse epilogues race — banned).
template<bool OUT_BF16, bool RELU, bool TRI = false, bool CTRUNC = false,
         bool QKV = false>
__global__ __launch_bounds__(512) void gemm_bt(
    int M, int N, int K,
    const bf16* __restrict__ Ap, long sAz, int lda,
    const bf16* __restrict__ Bp, long sBz, int ldbt,
    const float* __restrict__ biasp, int sBiasZ,
    void* __restrict__ Cp, long sCz, long sCb, long sCs, long sCn,
    void* __restrict__ Cp2 = nullptr, const float* __restrict__ bias2p = nullptr)
{
  extern __shared__ __align__(16) char lds[];   // 73728 B

  const int tid = threadIdx.x;
  // bijective XCD-aware block swizzle
  const int gx = gridDim.x, gy = gridDim.y;
  const int nwg = gx * gy * (int)gridDim.z;
  int flat = ((int)blockIdx.z * gy + (int)blockIdx.y) * gx + (int)blockIdx.x;
  {
    const int q = nwg >> 3, r = nwg & 7;
    const int xcd = flat & 7, loc = flat >> 3;
    flat = (xcd < r ? xcd * (q + 1) : r * (q + 1) + (xcd - r) * q) + loc;
  }
  int m0, n0, z;
  if (TRI) {                                  // 20 tiles: i rows of 256, j<=2i+1
    z = flat / 20;
    const int t = flat % 20;
    const int i = (t < 2) ? 0 : (t < 6) ? 1 : (t < 12) ? 2 : 3;
    const int cum[4] = {0, 2, 6, 12};
    const int j = t - cum[i];
    m0 = i * 256; n0 = j * 128;
  } else {
    const int bx  = flat % gx;
    const int byz = flat / gx;
    m0 = bx * 256;
    n0 = (byz % gy) * 128;
    z  = byz / gy;
  }
  const int KK = CTRUNC ? min(K, m0 + 256) : K;

  const int lane = tid & 63;
  const int wid  = tid >> 6;          // 0..7
  const int wm = (wid >> 1) * 64;     // 0,64,128,192
  const int wn = (wid & 1) * 64;      // 0,64

  const int srow  = tid >> 2;         // 0..127
  const int sslot = tid & 3;
  const int xorb  = (sslot ^ (srow & 3)) << 4;   // (srow+128)&3 == srow&3

  const char* gA0 = (const char*)(Ap + (long)z * sAz + (long)(m0 + srow) * lda) + xorb;
  const char* gA1 = (const char*)(Ap + (long)z * sAz + (long)(m0 + srow + 128) * lda) + xorb;
  const char* gB0 = (const char*)(Bp + (long)z * sBz + (long)(n0 + srow) * ldbt) + xorb;

  auto stage = [&](int bo) {          // 3 loads/thread: A 16K (2) + B 8K (1)
    gload16(gA0, lds + bo + tid * 16);
    gload16(gA1, lds + bo + 8192 + tid * 16);
    gload16(gB0, lds + bo + 16384 + tid * 16);
    gA0 += 64; gA1 += 64; gB0 += 64;
  };

  const int fr = lane & 15;
  const int kq = lane >> 4;
  int fA[4], fB[4];
#pragma unroll
  for (int m = 0; m < 4; ++m) {
    const int R = wm + m * 16 + fr;   // 0..255
    fA[m] = R * 64 + ((kq ^ (R & 3)) << 4);
  }
#pragma unroll
  for (int n = 0; n < 4; ++n) {
    const int R = wn + n * 16 + fr;   // 0..127
    fB[n] = 16384 + R * 64 + ((kq ^ (R & 3)) << 4);
  }

  f32x4 acc[4][4] = {};

  const int nt = KK >> 5;             // >= 2 at every call site
  stage(0);
  stage(24576);
  int cur = 0;
  int nb  = 2;
  for (int t = 0; t < nt; ++t) {
    if (t + 1 < nt) {
      asm volatile("s_waitcnt vmcnt(3)" ::: "memory");   // tile t landed
    } else {
      asm volatile("s_waitcnt vmcnt(0)" ::: "memory");
    }
    __builtin_amdgcn_s_barrier();     // t resident; all waves done compute(t-1)
    if (t + 2 < nt) stage(nb * 24576);
    const int co = cur * 24576;
    bf16x8 af[4], bfr[4];
#pragma unroll
    for (int m = 0; m < 4; ++m) af[m] = *(const bf16x8*)(lds + co + fA[m]);
#pragma unroll
    for (int n = 0; n < 4; ++n) bfr[n] = *(const bf16x8*)(lds + co + fB[n]);
#pragma unroll
    for (int m = 0; m < 4; ++m)
#pragma unroll
      for (int n = 0; n < 4; ++n)
        acc[m][n] = __builtin_amdgcn_mfma_f32_16x16x32_bf16(af[m], bfr[n], acc[m][n], 0, 0, 0);
    cur = (cur == 2) ? 0 : cur + 1;
    nb  = (nb == 2) ? 0 : nb + 1;
  }

  // ---- epilogue (direct stores): C/D layout col=lane&15, row=(lane>>4)*4+reg ----
  const int rg = (lane >> 4) * 4;
  const int cl = lane & 15;

  if (QKV) {
    if (n0 == 0) {
      // qk tile: qk[b][z][s][128], b=grow>>10, s=grow&1023
#pragma unroll
      for (int n = 0; n < 4; ++n) {
        const int gcol = wn + n * 16 + cl;
        const float bias = biasp[z * 128 + gcol];
#pragma unroll
        for (int m = 0; m < 4; ++m) {
#pragma unroll
          for (int rr = 0; rr < 4; ++rr) {
            const int grow = m0 + wm + m * 16 + rg + rr;
            const int bb = grow >> 10, s = grow & 1023;
            ((bf16*)Cp)[((long)(bb * NH + z) * SQ + s) * 128 + gcol] =
                __float2bfloat16(acc[m][n][rr] + bias);
          }
        }
      }
    } else {
      // vT tile: vT[b][z][e][s], e = n0-128+..., s contiguous -> ushort4
#pragma unroll
      for (int n = 0; n < 4; ++n) {
        const int e = n0 - 128 + wn + n * 16 + cl;
        const float bias = bias2p[z * DM + e];
#pragma unroll
        for (int m = 0; m < 4; ++m) {
          const int grow = m0 + wm + m * 16 + rg;
          const int bb = grow >> 10, s = grow & 1023;   // rr-run stays in one b
          const long ci = ((long)(bb * NH + z) * DM + e) * SQ + s;
          ushort4 pk;
          pk.x = __builtin_bit_cast(ushort, __float2bfloat16(acc[m][n][0] + bias));
          pk.y = __builtin_bit_cast(ushort, __float2bfloat16(acc[m][n][1] + bias));
          pk.z = __builtin_bit_cast(ushort, __float2bfloat16(acc[m][n][2] + bias));
          pk.w = __builtin_bit_cast(ushort, __float2bfloat16(acc[m][n][3] + bias));
          *(ushort4*)((bf16*)Cp2 + ci) = pk;
        }
      }
    }
    return;
  }

  const long zb = (long)z * sBiasZ;
#pragma unroll
  for (int n = 0; n < 4; ++n) {
    const int gcol = n0 + wn + n * 16 + cl;
    const float bias = biasp ? biasp[zb + gcol] : 0.f;
    if (OUT_BF16 && sCs == 1) {
#pragma unroll
      for (int m = 0; m < 4; ++m) {
        const int grow = m0 + wm + m * 16 + rg;
        const long ci = (long)z * sCz + (long)(grow >> 10) * sCb
                      + (long)(grow & 1023) + (long)gcol * sCn;
        ushort4 pk;
        float v0 = acc[m][n][0] + bias, v1 = acc[m][n][1] + bias;
        float v2 = acc[m][n][2] + bias, v3 = acc[m][n][3] + bias;
        if (RELU) { v0 = fmaxf(v0, 0.f); v1 = fmaxf(v1, 0.f);
                    v2 = fmaxf(v2, 0.f); v3 = fmaxf(v3, 0.f); }
        pk.x = __builtin_bit_cast(ushort, __float2bfloat16(v0));
        pk.y = __builtin_bit_cast(ushort, __float2bfloat16(v1));
        pk.z = __builtin_bit_cast(ushort, __float2bfloat16(v2));
        pk.w = __builtin_bit_cast(ushort, __float2bfloat16(v3));
        *(ushort4*)((bf16*)Cp + ci) = pk;
      }
    } else {
#pragma unroll
      for (int m = 0; m < 4; ++m) {
#pragma unroll
        for (int rr = 0; rr < 4; ++rr) {
          const int grow = m0 + wm + m * 16 + rg + rr;
          float v = acc[m][n][rr] + bias;
          if (RELU) v = fmaxf(v, 0.f);
          const long ci = (long)z * sCz + (long)(grow >> 10) * sCb
                        + (long)(grow & 1023) * sCs + (long)gcol * sCn;
          if (OUT_BF16) ((bf16*)Cp)[ci] = __float2bfloat16(v);
          else          ((float*)Cp)[ci] = v;
        }
      }
    }
  }
}

// ---------------- shared 64x64 fp32->bf16 transpose body ----------------
__device__ __forceinline__ void transpose_tile(
    const float* __restrict__ in, int ldin, bf16* __restrict__ out, int ldout,
    int n0, int k0, int tid)
{
  __shared__ float t[64][65];
  const int cx = (tid & 15) * 4, ry = tid >> 4;
#pragma unroll
  for (int p = 0; p < 4; ++p) {
    const int k = ry + p * 16;
    const float4 v = *(const float4*)(in + (long)(k0 + k) * ldin + n0 + cx);
    t[k][cx] = v.x; t[k][cx + 1] = v.y; t[k][cx + 2] = v.z; t[k][cx + 3] = v.w;
  }
  __syncthreads();
#pragma unroll
  for (int p = 0; p < 4; ++p) {
    const int n = ry + p * 16;
    ushort4 o;
    o.x = __builtin_bit_cast(ushort, __float2bfloat16(t[cx + 0][n]));
    o.y = __builtin_bit_cast(ushort, __float2bfloat16(t[cx + 1][n]));
    o.z = __builtin_bit_cast(ushort, __float2bfloat16(t[cx + 2][n]));
    o.w = __builtin_bit_cast(ushort, __float2bfloat16(t[cx + 3][n]));
    *(ushort4*)(out + (long)(n0 + n) * ldout + k0 + cx) = o;
  }
}

// ---------------- standalone transpose (Wout) ----------------
__global__ __launch_bounds__(256) void transpose_kernel(
    const float* __restrict__ in, long sInZ, int ldin,
    bf16* __restrict__ out, long sOutZ, int ldout)
{
  transpose_tile(in + (long)blockIdx.z * sInZ, ldin,
                 out + (long)blockIdx.z * sOutZ, ldout,
                 blockIdx.x * 64, blockIdx.y * 64, threadIdx.x);
}

// ---------------- fused ATTENTION weight prep -> wqvT [H][896][D] ----------------
// ORDER CONSTRAINT (r16 bug): w1T/w2T alias wqvT; FF prep after QKV GEMM+vmeanw.
__global__ __launch_bounds__(256) void prep_attn_kernel(
    const float* __restrict__ Wq_l, const float* __restrict__ Wk_l,
    const float* __restrict__ Wv_l,
    const float* __restrict__ bq_l, const float* __restrict__ bk_l,
    bf16* __restrict__ wqvT, float* __restrict__ biasqk)
{
  const int tid = threadIdx.x;
  int f = blockIdx.x;
  if (f < 144) {
    const int h = f / 12, ky = f % 12;
    transpose_tile(Wq_l + (long)h * DM * KDH, KDH,
                   wqvT + (long)h * 896 * DM, DM, 0, ky * 64, tid);
  } else if (f < 288) {
    f -= 144;
    const int h = f / 12, ky = f % 12;
    transpose_tile(Wk_l + (long)h * DM * KDH, KDH,
                   wqvT + (long)h * 896 * DM + (long)64 * DM, DM, 0, ky * 64, tid);
  } else if (f < 2016) {
    f -= 288;
    const int h = f / 144, r = f % 144;
    transpose_tile(Wv_l + (long)h * DM * DM, DM,
                   wqvT + (long)h * 896 * DM + (long)128 * DM, DM,
                   (r % 12) * 64, (r / 12) * 64, tid);
  } else {
    const int i = (f - 2016) * 256 + tid;
    if (i < NH * 128) {
      const int h = i >> 7, n = i & 127;
      biasqk[i] = (n < 64) ? bq_l[h * 64 + n] : bk_l[h * 64 + n - 64];
    }
  }
}

// ---------------- fused FF weight prep ----------------
__global__ __launch_bounds__(256) void prep_ff_kernel(
    const float* __restrict__ W1_l, const float* __restrict__ W2_l,
    bf16* __restrict__ w1T, bf16* __restrict__ w2T)
{
  const int tid = threadIdx.x;
  int f = blockIdx.x;
  if (f < 576) {
    transpose_tile(W1_l, FFD, w1T, DM, (f % 48) * 64, (f / 48) * 64, tid);
  } else {
    f -= 576;
    transpose_tile(W2_l, DM, w2T, FFD, (f % 12) * 64, (f / 12) * 64, tid);
  }
}

// ---------------- xmean pipeline (analytic pad-row attention) ----------------
__global__ __launch_bounds__(256) void xpart_kernel(
    const float* __restrict__ x, float* __restrict__ xpart) {
  const int b = blockIdx.x, g = blockIdx.y;
  const int tid = threadIdx.x;
  const float* xp = x + (long)b * SQ * DM + (long)g * 64 * DM;
  float a0 = 0.f, a1 = 0.f, a2 = 0.f;
  for (int s = 0; s < 64; ++s) {
    a0 += xp[(long)s * DM + tid];
    a1 += xp[(long)s * DM + tid + 256];
    a2 += xp[(long)s * DM + tid + 512];
  }
  float* op = xpart + (long)(b * 16 + g) * DM;
  op[tid] = a0; op[tid + 256] = a1; op[tid + 512] = a2;
}

// vmean[b][e] = (1/H) * sum_h ( dot(xmean[b,:], wqvT[h,128+e,:]) + bv[h,e] )
__global__ __launch_bounds__(256) void vmeanw_kernel(
    const float* __restrict__ xpart, const bf16* __restrict__ wqvT,
    const float* __restrict__ bv, float* __restrict__ vmean) {
  const int tid = threadIdx.x;
  const int w = blockIdx.x * 4 + (tid >> 6);
  const int b = w / DM;
  const int e = w % DM;
  const int lane = tid & 63;
  float xm[12];
#pragma unroll
  for (int j = 0; j < 12; ++j) {
    float a = 0.f;
#pragma unroll
    for (int g = 0; g < 16; ++g)
      a += xpart[(long)(b * 16 + g) * DM + lane + j * 64];
    xm[j] = a * (1.0f / (float)SQ);
  }
  float acc = 0.f;
  for (int h = 0; h < NH; ++h) {
    const bf16* wr = wqvT + ((long)h * 896 + 128 + e) * DM;
#pragma unroll
    for (int j = 0; j < 12; ++j)
      acc += xm[j] * __bfloat162float(wr[lane + j * 64]);
  }
#pragma unroll
  for (int o = 32; o >= 1; o >>= 1) acc += __shfl_xor(acc, o);
  if (lane == 0) {
    float bs = 0.f;
#pragma unroll
    for (int h = 0; h < NH; ++h) bs += bv[h * DM + e];
    vmean[b * DM + e] = (acc + bs) * (1.0f / (float)NH);
  }
}

// ---------------- embedding + PE -> x fp32 + xb bf16 ----------------
__global__ __launch_bounds__(256) void embed_kernel(
    const int* __restrict__ tok, const float* __restrict__ emb,
    float* __restrict__ x, bf16* __restrict__ xb)
{
  const int gid = blockIdx.x * 256 + threadIdx.x;
  const int row = gid / (DM / 4);
  const int dc  = (gid % (DM / 4)) * 4;
  const int t = tok[row];
  const int s = row & (SQ - 1);
#pragma unroll
  for (int j = 0; j < 4; ++j) {
    const int d = dc + j;
    const float e = emb[(long)t * DM + d];
    const float div = expf(-(float)(d & ~1) * (9.210340371976184f / (float)DM));
    const float ang = (float)s * div;
    const float pe = (d & 1) ? cosf(ang) : sinf(ang);
    const float v = e + pe;
    x[(long)row * DM + d] = v;
    xb[(long)row * DM + d] = __float2bfloat16(v);
  }
}

// ---------------- masked softmax, causal-truncated ----------------
// Writes cols [0, (s|255)+1): zero-fill beyond the causal limit so the
// BM=256 CTRUNC-PV (reads cols < m0+256) never sees stale data.
__global__ __launch_bounds__(256) void softmax_kernel(
    bf16* __restrict__ P, const int* __restrict__ tok)
{
  const int row = blockIdx.x;
  const int s = row & (SQ - 1);
  const int z = row >> 10;
  const int b = z / NH;
  const int* tb = tok + b * SQ;
  if (tb[s] == 0) return;
  bf16* sp = P + (long)row * SQ;
  const int tid = threadIdx.x;
  const int t0 = tid * 4;
  const int Lw = (s | 255) + 1;       // write range (tile-aligned for PV)
  const bool act = t0 < Lw;

  float val[4] = {-1e30f, -1e30f, -1e30f, -1e30f};
  float vmax = -1e30f;
  if (act) {
    uint2 raw = *(const uint2*)(sp + t0);
    int4 tv = *(const int4*)(tb + t0);
    const bf16* rh = (const bf16*)&raw;
    const int tvv[4] = {tv.x, tv.y, tv.z, tv.w};
#pragma unroll
    for (int j = 0; j < 4; ++j) {
      const int t = t0 + j;
      const bool valid = (t <= s) && (tvv[j] != 0);
      val[j] = valid ? __bfloat162float(rh[j]) * 0.125f : -1e30f;
      vmax = fmaxf(vmax, val[j]);
    }
  }
  __shared__ float red[4];
  const int lane = tid & 63, wid = tid >> 6;
  float w = vmax;
#pragma unroll
  for (int o = 32; o >= 1; o >>= 1) w = fmaxf(w, __shfl_xor(w, o));
  if (lane == 0) red[wid] = w;
  __syncthreads();
  const float Mx = fmaxf(fmaxf(red[0], red[1]), fmaxf(red[2], red[3]));
  __syncthreads();
  float e[4]; float lsum = 0.f;
#pragma unroll
  for (int j = 0; j < 4; ++j) {
    e[j] = (val[j] > -1e29f) ? expf(val[j] - Mx) : 0.f;
    lsum += e[j];
  }
  w = lsum;
#pragma unroll
  for (int o = 32; o >= 1; o >>= 1) w += __shfl_xor(w, o);
  if (lane == 0) red[wid] = w;
  __syncthreads();
  const float inv = 1.0f / (red[0] + red[1] + red[2] + red[3]);
  if (act) {
    ushort4 pk;
    pk.x = __builtin_bit_cast(ushort, __float2bfloat16(e[0] * inv));
    pk.y = __builtin_bit_cast(ushort, __float2bfloat16(e[1] * inv));
    pk.z = __builtin_bit_cast(ushort, __float2bfloat16(e[2] * inv));
    pk.w = __builtin_bit_cast(ushort, __float2bfloat16(e[3] * inv));
    *(ushort4*)(sp + t0) = pk;
  }
}

// ---------------- residual + LayerNorm, vectorized ----------------
#define TCHUNK 1572864L
template<int MODE>
__global__ __launch_bounds__(256) void ln_kernel(
    float* __restrict__ x, bf16* __restrict__ xb,
    const float* __restrict__ tmp, const bf16* __restrict__ heads,
    const float* __restrict__ g, const float* __restrict__ be,
    const int* __restrict__ tok, const float* __restrict__ vmean,
    const float* __restrict__ bias)
{
  const int r = blockIdx.x;
  const int b = r >> 10;
  const int s = r & (SQ - 1);
  const int tid = threadIdx.x;
  __shared__ float rs[4], rq[4];
  const bool pad = (MODE == 1) && (tok[r] == 0);
  float sum = 0.f, sq = 0.f;
  float v[8];
  if (tid < 96) {
    const int d0 = tid * 8;
    const float4 x0 = *(const float4*)(x + (long)r * DM + d0);
    const float4 x1 = *(const float4*)(x + (long)r * DM + d0 + 4);
    v[0] = x0.x; v[1] = x0.y; v[2] = x0.z; v[3] = x0.w;
    v[4] = x1.x; v[5] = x1.y; v[6] = x1.z; v[7] = x1.w;
    if (MODE == 0) {
#pragma unroll
      for (int c = 0; c < 4; ++c) {
        const float* tp = tmp + c * TCHUNK + (long)r * DM + d0;
        const float4 t0_ = *(const float4*)tp;
        const float4 t1_ = *(const float4*)(tp + 4);
        v[0] += t0_.x; v[1] += t0_.y; v[2] += t0_.z; v[3] += t0_.w;
        v[4] += t1_.x; v[5] += t1_.y; v[6] += t1_.z; v[7] += t1_.w;
      }
      const float4 b0_ = *(const float4*)(bias + d0);
      const float4 b1_ = *(const float4*)(bias + d0 + 4);
      v[0] += b0_.x; v[1] += b0_.y; v[2] += b0_.z; v[3] += b0_.w;
      v[4] += b1_.x; v[5] += b1_.y; v[6] += b1_.z; v[7] += b1_.w;
    } else if (pad) {
      const float4 t0_ = *(const float4*)(vmean + b * DM + d0);
      const float4 t1_ = *(const float4*)(vmean + b * DM + d0 + 4);
      v[0] += t0_.x; v[1] += t0_.y; v[2] += t0_.z; v[3] += t0_.w;
      v[4] += t1_.x; v[5] += t1_.y; v[6] += t1_.z; v[7] += t1_.w;
    } else {
      float hs[8] = {0.f, 0.f, 0.f, 0.f, 0.f, 0.f, 0.f, 0.f};
      for (int h = 0; h < NH; ++h) {
        union { uint4 u; ushort us[8]; } hv;
        hv.u = *(const uint4*)(heads + ((long)(b * NH + h) * SQ + s) * DM + d0);
#pragma unroll
        for (int j = 0; j < 8; ++j)
          hs[j] += __bfloat162float(__builtin_bit_cast(bf16, hv.us[j]));
      }
#pragma unroll
      for (int j = 0; j < 8; ++j) v[j] += hs[j] * (1.0f / (float)NH);
    }
#pragma unroll
    for (int j = 0; j < 8; ++j) { sum += v[j]; sq += v[j] * v[j]; }
  }
  const int lane = tid & 63, wid = tid >> 6;
  float s1 = sum, s2 = sq;
#pragma unroll
  for (int o = 32; o >= 1; o >>= 1) { s1 += __shfl_xor(s1, o); s2 += __shfl_xor(s2, o); }
  if (lane == 0) { rs[wid] = s1; rq[wid] = s2; }
  __syncthreads();
  const float S1 = rs[0] + rs[1] + rs[2] + rs[3];
  const float S2 = rq[0] + rq[1] + rq[2] + rq[3];
  const float mean = S1 * (1.0f / (float)DM);
  const float var  = S2 * (1.0f / (float)DM) - mean * mean;
  const float rstd = rsqrtf(var + 1e-5f);
  if (tid < 96) {
    const int d0 = tid * 8;
    const float4 g0 = *(const float4*)(g + d0);
    const float4 g1 = *(const float4*)(g + d0 + 4);
    const float4 b0 = *(const float4*)(be + d0);
    const float4 b1 = *(const float4*)(be + d0 + 4);
    float o[8];
    o[0] = (v[0] - mean) * rstd * g0.x + b0.x;
    o[1] = (v[1] - mean) * rstd * g0.y + b0.y;
    o[2] = (v[2] - mean) * rstd * g0.z + b0.z;
    o[3] = (v[3] - mean) * rstd * g0.w + b0.w;
    o[4] = (v[4] - mean) * rstd * g1.x + b1.x;
    o[5] = (v[5] - mean) * rstd * g1.y + b1.y;
    o[6] = (v[6] - mean) * rstd * g1.z + b1.z;
    o[7] = (v[7] - mean) * rstd * g1.w + b1.w;
    *(float4*)(x + (long)r * DM + d0)     = make_float4(o[0], o[1], o[2], o[3]);
    *(float4*)(x + (long)r * DM + d0 + 4) = make_float4(o[4], o[5], o[6], o[7]);
    union { uint4 u; ushort us[8]; } pk;
#pragma unroll
    for (int j = 0; j < 8; ++j)
      pk.us[j] = __builtin_bit_cast(ushort, __float2bfloat16(o[j]));
    *(uint4*)(xb + (long)r * DM + d0) = pk.u;
  }
}

extern "C" void kernel_launch(void* const* d_in, const int* in_sizes, int n_in,
                              void* d_out, int out_size, void* d_ws, size_t ws_size,
                              hipStream_t stream) {
  const int expect_sizes[18] = {
    2048, 24576000, 3538944, 4608, 3538944, 4608, 42467328, 55296,
    4608, 4608, 4608, 4608, 14155776, 18432, 14155776, 4608, 24576000, 32000
  };
  bool sizes_ok = (n_in == 18);
  if (sizes_ok)
    for (int i = 0; i < 18; ++i) sizes_ok = sizes_ok && (in_sizes[i] == expect_sizes[i]);
  if (!sizes_ok) {
    fill_kernel<<<2048, 256, 0, stream>>>((float*)d_out, (long)out_size, 1000.0f);
    return;
  }
  if (out_size != 65536000) {
    fill_kernel<<<2048, 256, 0, stream>>>((float*)d_out, (long)out_size, 3000.0f);
    return;
  }
  if (ws_size < 158189568ull) {
    fill_kernel<<<2048, 256, 0, stream>>>((float*)d_out, (long)out_size, 2000.0f);
    return;
  }

  // raise dynamic-LDS cap for all used gemm instantiations (host-side, idempotent)
  (void)hipFuncSetAttribute((const void*)&gemm_bt<true, false, false, false, true>,
      hipFuncAttributeMaxDynamicSharedMemorySize, 73728);
  (void)hipFuncSetAttribute((const void*)&gemm_bt<true, false, true, false, false>,
      hipFuncAttributeMaxDynamicSharedMemorySize, 73728);
  (void)hipFuncSetAttribute((const void*)&gemm_bt<true, false, false, true, false>,
      hipFuncAttributeMaxDynamicSharedMemorySize, 73728);
  (void)hipFuncSetAttribute((const void*)&gemm_bt<true, true, false, false, false>,
      hipFuncAttributeMaxDynamicSharedMemorySize, 73728);
  (void)hipFuncSetAttribute((const void*)&gemm_bt<false, false, false, false, false>,
      hipFuncAttributeMaxDynamicSharedMemorySize, 73728);

  const int*   tok  = (const int*)d_in[0];
  const float* emb  = (const float*)d_in[1];
  const float* Wq   = (const float*)d_in[2];
  const float* bq   = (const float*)d_in[3];
  const float* Wk   = (const float*)d_in[4];
  const float* bk   = (const float*)d_in[5];
  const float* Wv   = (const float*)d_in[6];
  const float* bv   = (const float*)d_in[7];
  const float* g1   = (const float*)d_in[8];
  const float* be1  = (const float*)d_in[9];
  const float* g2   = (const float*)d_in[10];
  const float* be2  = (const float*)d_in[11];
  const float* W1   = (const float*)d_in[12];
  const float* b1   = (const float*)d_in[13];
  const float* W2   = (const float*)d_in[14];
  const float* b2   = (const float*)d_in[15];
  const float* Wout = (const float*)d_in[16];
  const float* bout = (const float*)d_in[17];

  char* ws = (char*)d_ws;
  float* x      = (float*)(ws + 0);
  bf16*  xb     = (bf16*) (ws + 6291456);
  bf16*  qk     = (bf16*) (ws + 9437184);
  bf16*  vT     = (bf16*) (ws + 15728640);
  float* tmp    = (float*)(ws + 15728640);
  bf16*  P      = (bf16*) (ws + 53477376);
  bf16*  woutT  = (bf16*) (ws + 53477376);
  bf16*  heads  = (bf16*) (ws + 103809024);
  bf16*  wqvT   = (bf16*) (ws + 141557760);    // [H][896][D] bf16
  bf16*  w1T    = (bf16*) (ws + 141557760);    // FF phase (aliases wqvT)
  bf16*  w2T    = (bf16*) (ws + 146276352);
  float* biasqk = (float*)(ws + 158072832);
  float* xpart  = (float*)(ws + 158078976);
  float* vmean  = (float*)(ws + 158183424);

  embed_kernel<<<dim3((2 * SQ * DM / 4) / 256), 256, 0, stream>>>(tok, emb, x, xb);

  for (int l = 0; l < NL; ++l) {
    prep_attn_kernel<<<dim3(2022), 256, 0, stream>>>(
        Wq + (long)l * NH * DM * KDH, Wk + (long)l * NH * DM * KDH,
        Wv + (long)l * NH * DM * DM,
        bq + l * NH * KDH, bk + l * NH * KDH,
        wqvT, biasqk);

    xpart_kernel<<<dim3(2, 16), 256, 0, stream>>>(x, xpart);
    vmeanw_kernel<<<dim3(384), 256, 0, stream>>>(xpart, wqvT, bv + (long)l * NH * DM, vmean);

    // fused Q|K|V projection: BM=256 -> grid (8,7,12)
    gemm_bt<true, false, false, false, true><<<dim3(8, 7, NH), 512, 73728, stream>>>(
        2048, 896, DM, xb, 0, DM, wqvT, (long)896 * DM, DM,
        biasqk, 128,
        qk, 0, 0, 0, 0,
        vT, bv + (long)l * NH * DM);
    // scores = Q @ K^T -> P  (20 triangular 256x128 tiles x 24)
    gemm_bt<true, false, true, false><<<dim3(20, 1, 2 * NH), 512, 73728, stream>>>(
        SQ, SQ, KDH, qk, (long)SQ * 128, 128, qk + 64, (long)SQ * 128, 128,
        (const float*)nullptr, 0,
        P, (long)SQ * SQ, 0, SQ, 1);
    softmax_kernel<<<dim3(2 * NH * SQ), 256, 0, stream>>>(P, tok);
    // heads = P @ V (causal K-truncation to m0+256)
    gemm_bt<true, false, false, true><<<dim3(4, 6, 2 * NH), 512, 73728, stream>>>(
        SQ, DM, SQ, P, (long)SQ * SQ, SQ, vT, (long)DM * SQ, SQ,
        (const float*)nullptr, 0,
        heads, (long)SQ * DM, 0, DM, 1);
    ln_kernel<1><<<dim3(2048), 256, 0, stream>>>(x, xb, nullptr, heads,
                                                 g1 + l * DM, be1 + l * DM, tok, vmean,
                                                 nullptr);
    prep_ff_kernel<<<dim3(1152), 256, 0, stream>>>(
        W1 + (long)l * DM * FFD, W2 + (long)l * FFD * DM, w1T, w2T);
    gemm_bt<true, true><<<dim3(8, 24, 1), 512, 73728, stream>>>(
        2048, FFD, DM, xb, 0, DM, w1T, 0, DM,
        b1 + (long)l * FFD, 0,
        (bf16*)P, 0, (long)SQ * FFD, FFD, 1);
    gemm_bt<false, false><<<dim3(8, 6, 4), 512, 73728, stream>>>(
        2048, DM, 768, (bf16*)P, 768, FFD, w2T, 768, FFD,
        (const float*)nullptr, 0,
        tmp, TCHUNK, (long)SQ * DM, DM, 1);
    ln_kernel<0><<<dim3(2048), 256, 0, stream>>>(x, xb, tmp, nullptr,
                                                 g2 + l * DM, be2 + l * DM, tok, nullptr,
                                                 b2 + (long)l * DM);
  }
  transpose_kernel<<<dim3(500, 12, 1), 256, 0, stream>>>(Wout, 0, NV, woutT, 0, DM);
  gemm_bt<false, false><<<dim3(8, 250, 1), 512, 73728, stream>>>(
      2048, NV, DM, xb, 0, DM, woutT, 0, DM,
      bout, 0,
      d_out, 0, (long)SQ * NV, NV, 1);
}

// Round 22
// 1548.937 us; speedup vs baseline: 1.0239x; 1.0239x over previous
//
#include <hip/hip_runtime.h>
#include <hip/hip_bf16.h>

#define SQ 1024
#define DM 768
#define NH 12
#define NL 6
#define NV 32000
#define KDH 64
#define FFD 3072

using bf16 = __hip_bfloat16;
typedef __attribute__((ext_vector_type(4))) float f32x4;
typedef __attribute__((ext_vector_type(8))) short bf16x8;

// ---------------- diagnostic fill (fp32 out) ----------------
__global__ void fill_kernel(float* __restrict__ out, long n, float val) {
  const long stride = (long)gridDim.x * blockDim.x;
  for (long i = (long)blockIdx.x * blockDim.x + threadIdx.x; i < n; i += stride)
    out[i] = val;
}

// async global->LDS, 16 bytes per lane
__device__ __forceinline__ void gload16(const void* g, void* l) {
  __builtin_amdgcn_global_load_lds(
      (const __attribute__((address_space(1))) unsigned int*)g,
      (__attribute__((address_space(3))) unsigned int*)l, 16, 0, 0);
}

// ---------------- 128x128 MFMA GEMM, 3-buf 2-ahead, one barrier/K (r20 form) ----------------
// For per-layer GEMMs (small grids: BM=128 keeps blocks/CU high — r21 lesson).
// TRI: 36-tile causal grid. CTRUNC: K -> m0+128. QKV: fused Q|K|V routing.
// Epilogue: DIRECT stores only (r13/r14: LDS-reuse epilogues race — banned).
template<bool OUT_BF16, bool RELU, bool TRI = false, bool CTRUNC = false,
         bool QKV = false>
__global__ __launch_bounds__(256) void gemm_bt(
    int M, int N, int K,
    const bf16* __restrict__ Ap, long sAz, int lda,
    const bf16* __restrict__ Bp, long sBz, int ldbt,
    const float* __restrict__ biasp, int sBiasZ,
    void* __restrict__ Cp, long sCz, long sCb, long sCs, long sCn,
    void* __restrict__ Cp2 = nullptr, const float* __restrict__ bias2p = nullptr)
{
  __shared__ __align__(16) char lds[49152];   // 3 bufs x (A 8K | B 8K)

  const int tid = threadIdx.x;
  const int gx = gridDim.x, gy = gridDim.y;
  const int nwg = gx * gy * (int)gridDim.z;
  int flat = ((int)blockIdx.z * gy + (int)blockIdx.y) * gx + (int)blockIdx.x;
  {
    const int q = nwg >> 3, r = nwg & 7;
    const int xcd = flat & 7, loc = flat >> 3;
    flat = (xcd < r ? xcd * (q + 1) : r * (q + 1) + (xcd - r) * q) + loc;
  }
  int m0, n0, z;
  if (TRI) {                                  // 36 triangle tiles, i>=j
    z = flat / 36;
    const int t = flat % 36;
    int i = (int)((sqrtf(8.0f * (float)t + 1.0f) - 1.0f) * 0.5f);
    if ((i + 1) * (i + 2) / 2 <= t) ++i;
    if (i * (i + 1) / 2 > t) --i;
    const int j = t - i * (i + 1) / 2;
    m0 = i * 128; n0 = j * 128;
  } else {
    const int bx  = flat % gx;
    const int byz = flat / gx;
    m0 = bx * 128;
    n0 = (byz % gy) * 128;
    z  = byz / gy;
  }
  const int KK = CTRUNC ? min(K, m0 + 128) : K;

  const int lane = tid & 63;
  const int wid  = tid >> 6;
  const int wm = (wid >> 1) * 64;
  const int wn = (wid & 1) * 64;

  const int srow  = tid >> 2;
  const int sslot = tid & 3;
  const int xorb  = (sslot ^ (srow & 3)) << 4;

  const char* gA0 = (const char*)(Ap + (long)z * sAz + (long)(m0 + srow) * lda) + xorb;
  const char* gA1 = (const char*)(Ap + (long)z * sAz + (long)(m0 + srow + 64) * lda) + xorb;
  const char* gB0 = (const char*)(Bp + (long)z * sBz + (long)(n0 + srow) * ldbt) + xorb;
  const char* gB1 = (const char*)(Bp + (long)z * sBz + (long)(n0 + srow + 64) * ldbt) + xorb;

  auto stage = [&](int bo) {
    gload16(gA0, lds + bo + tid * 16);
    gload16(gA1, lds + bo + (tid + 256) * 16);
    gload16(gB0, lds + bo + 8192 + tid * 16);
    gload16(gB1, lds + bo + 8192 + (tid + 256) * 16);
    gA0 += 64; gA1 += 64; gB0 += 64; gB1 += 64;
  };

  const int fr = lane & 15;
  const int kq = lane >> 4;
  int fA[4], fB[4];
#pragma unroll
  for (int m = 0; m < 4; ++m) {
    const int R = wm + m * 16 + fr;
    fA[m] = R * 64 + ((kq ^ (R & 3)) << 4);
  }
#pragma unroll
  for (int n = 0; n < 4; ++n) {
    const int R = wn + n * 16 + fr;
    fB[n] = 8192 + R * 64 + ((kq ^ (R & 3)) << 4);
  }

  f32x4 acc[4][4] = {};

  const int nt = KK >> 5;
  stage(0);
  stage(16384);
  int cur = 0;
  int nb  = 2;
  for (int t = 0; t < nt; ++t) {
    if (t + 1 < nt) {
      asm volatile("s_waitcnt vmcnt(4)" ::: "memory");
    } else {
      asm volatile("s_waitcnt vmcnt(0)" ::: "memory");
    }
    __builtin_amdgcn_s_barrier();
    if (t + 2 < nt) stage(nb * 16384);
    const int co = cur * 16384;
    bf16x8 af[4], bfr[4];
#pragma unroll
    for (int m = 0; m < 4; ++m) af[m] = *(const bf16x8*)(lds + co + fA[m]);
#pragma unroll
    for (int n = 0; n < 4; ++n) bfr[n] = *(const bf16x8*)(lds + co + fB[n]);
#pragma unroll
    for (int m = 0; m < 4; ++m)
#pragma unroll
      for (int n = 0; n < 4; ++n)
        acc[m][n] = __builtin_amdgcn_mfma_f32_16x16x32_bf16(af[m], bfr[n], acc[m][n], 0, 0, 0);
    cur = (cur == 2) ? 0 : cur + 1;
    nb  = (nb == 2) ? 0 : nb + 1;
  }

  const int rg = (lane >> 4) * 4;
  const int cl = lane & 15;

  if (QKV) {
    if (n0 == 0) {
#pragma unroll
      for (int n = 0; n < 4; ++n) {
        const int gcol = wn + n * 16 + cl;
        const float bias = biasp[z * 128 + gcol];
#pragma unroll
        for (int m = 0; m < 4; ++m) {
#pragma unroll
          for (int rr = 0; rr < 4; ++rr) {
            const int grow = m0 + wm + m * 16 + rg + rr;
            const int bb = grow >> 10, s = grow & 1023;
            ((bf16*)Cp)[((long)(bb * NH + z) * SQ + s) * 128 + gcol] =
                __float2bfloat16(acc[m][n][rr] + bias);
          }
        }
      }
    } else {
#pragma unroll
      for (int n = 0; n < 4; ++n) {
        const int e = n0 - 128 + wn + n * 16 + cl;
        const float bias = bias2p[z * DM + e];
#pragma unroll
        for (int m = 0; m < 4; ++m) {
          const int grow = m0 + wm + m * 16 + rg;
          const int bb = grow >> 10, s = grow & 1023;
          const long ci = ((long)(bb * NH + z) * DM + e) * SQ + s;
          ushort4 pk;
          pk.x = __builtin_bit_cast(ushort, __float2bfloat16(acc[m][n][0] + bias));
          pk.y = __builtin_bit_cast(ushort, __float2bfloat16(acc[m][n][1] + bias));
          pk.z = __builtin_bit_cast(ushort, __float2bfloat16(acc[m][n][2] + bias));
          pk.w = __builtin_bit_cast(ushort, __float2bfloat16(acc[m][n][3] + bias));
          *(ushort4*)((bf16*)Cp2 + ci) = pk;
        }
      }
    }
    return;
  }

  const long zb = (long)z * sBiasZ;
#pragma unroll
  for (int n = 0; n < 4; ++n) {
    const int gcol = n0 + wn + n * 16 + cl;
    const float bias = biasp ? biasp[zb + gcol] : 0.f;
    if (OUT_BF16 && sCs == 1) {
#pragma unroll
      for (int m = 0; m < 4; ++m) {
        const int grow = m0 + wm + m * 16 + rg;
        const long ci = (long)z * sCz + (long)(grow >> 10) * sCb
                      + (long)(grow & 1023) + (long)gcol * sCn;
        ushort4 pk;
        float v0 = acc[m][n][0] + bias, v1 = acc[m][n][1] + bias;
        float v2 = acc[m][n][2] + bias, v3 = acc[m][n][3] + bias;
        if (RELU) { v0 = fmaxf(v0, 0.f); v1 = fmaxf(v1, 0.f);
                    v2 = fmaxf(v2, 0.f); v3 = fmaxf(v3, 0.f); }
        pk.x = __builtin_bit_cast(ushort, __float2bfloat16(v0));
        pk.y = __builtin_bit_cast(ushort, __float2bfloat16(v1));
        pk.z = __builtin_bit_cast(ushort, __float2bfloat16(v2));
        pk.w = __builtin_bit_cast(ushort, __float2bfloat16(v3));
        *(ushort4*)((bf16*)Cp + ci) = pk;
      }
    } else {
#pragma unroll
      for (int m = 0; m < 4; ++m) {
#pragma unroll
        for (int rr = 0; rr < 4; ++rr) {
          const int grow = m0 + wm + m * 16 + rg + rr;
          float v = acc[m][n][rr] + bias;
          if (RELU) v = fmaxf(v, 0.f);
          const long ci = (long)z * sCz + (long)(grow >> 10) * sCb
                        + (long)(grow & 1023) * sCs + (long)gcol * sCn;
          if (OUT_BF16) ((bf16*)Cp)[ci] = __float2bfloat16(v);
          else          ((float*)Cp)[ci] = v;
        }
      }
    }
  }
}

// ---------------- 256x128 MFMA GEMM, 512 thr — LOGITS ONLY (r21 form) ----------------
// Wins only on big grids (2000 blocks): 16 waves/CU, same serial path/barrier.
__global__ __launch_bounds__(512) void gemm256(
    int M, int N, int K,
    const bf16* __restrict__ Ap, int lda,
    const bf16* __restrict__ Bp, int ldbt,
    const float* __restrict__ biasp,
    float* __restrict__ Cp, long sCb, long sCn)
{
  extern __shared__ __align__(16) char lds[];   // 73728 B

  const int tid = threadIdx.x;
  const int gx = gridDim.x, gy = gridDim.y;
  const int nwg = gx * gy;
  int flat = (int)blockIdx.y * gx + (int)blockIdx.x;
  {
    const int q = nwg >> 3, r = nwg & 7;
    const int xcd = flat & 7, loc = flat >> 3;
    flat = (xcd < r ? xcd * (q + 1) : r * (q + 1) + (xcd - r) * q) + loc;
  }
  const int m0 = (flat % gx) * 256;
  const int n0 = (flat / gx) * 128;

  const int lane = tid & 63;
  const int wid  = tid >> 6;
  const int wm = (wid >> 1) * 64;
  const int wn = (wid & 1) * 64;

  const int srow  = tid >> 2;
  const int sslot = tid & 3;
  const int xorb  = (sslot ^ (srow & 3)) << 4;

  const char* gA0 = (const char*)(Ap + (long)(m0 + srow) * lda) + xorb;
  const char* gA1 = (const char*)(Ap + (long)(m0 + srow + 128) * lda) + xorb;
  const char* gB0 = (const char*)(Bp + (long)(n0 + srow) * ldbt) + xorb;

  auto stage = [&](int bo) {
    gload16(gA0, lds + bo + tid * 16);
    gload16(gA1, lds + bo + 8192 + tid * 16);
    gload16(gB0, lds + bo + 16384 + tid * 16);
    gA0 += 64; gA1 += 64; gB0 += 64;
  };

  const int fr = lane & 15;
  const int kq = lane >> 4;
  int fA[4], fB[4];
#pragma unroll
  for (int m = 0; m < 4; ++m) {
    const int R = wm + m * 16 + fr;
    fA[m] = R * 64 + ((kq ^ (R & 3)) << 4);
  }
#pragma unroll
  for (int n = 0; n < 4; ++n) {
    const int R = wn + n * 16 + fr;
    fB[n] = 16384 + R * 64 + ((kq ^ (R & 3)) << 4);
  }

  f32x4 acc[4][4] = {};

  const int nt = K >> 5;
  stage(0);
  stage(24576);
  int cur = 0;
  int nb  = 2;
  for (int t = 0; t < nt; ++t) {
    if (t + 1 < nt) {
      asm volatile("s_waitcnt vmcnt(3)" ::: "memory");
    } else {
      asm volatile("s_waitcnt vmcnt(0)" ::: "memory");
    }
    __builtin_amdgcn_s_barrier();
    if (t + 2 < nt) stage(nb * 24576);
    const int co = cur * 24576;
    bf16x8 af[4], bfr[4];
#pragma unroll
    for (int m = 0; m < 4; ++m) af[m] = *(const bf16x8*)(lds + co + fA[m]);
#pragma unroll
    for (int n = 0; n < 4; ++n) bfr[n] = *(const bf16x8*)(lds + co + fB[n]);
#pragma unroll
    for (int m = 0; m < 4; ++m)
#pragma unroll
      for (int n = 0; n < 4; ++n)
        acc[m][n] = __builtin_amdgcn_mfma_f32_16x16x32_bf16(af[m], bfr[n], acc[m][n], 0, 0, 0);
    cur = (cur == 2) ? 0 : cur + 1;
    nb  = (nb == 2) ? 0 : nb + 1;
  }

  const int rg = (lane >> 4) * 4;
  const int cl = lane & 15;
#pragma unroll
  for (int n = 0; n < 4; ++n) {
    const int gcol = n0 + wn + n * 16 + cl;
    const float bias = biasp[gcol];
#pragma unroll
    for (int m = 0; m < 4; ++m) {
#pragma unroll
      for (int rr = 0; rr < 4; ++rr) {
        const int grow = m0 + wm + m * 16 + rg + rr;
        Cp[(long)grow * sCb + (long)gcol * sCn] = acc[m][n][rr] + bias;
      }
    }
  }
}

// ---------------- shared 64x64 fp32->bf16 transpose body ----------------
__device__ __forceinline__ void transpose_tile(
    const float* __restrict__ in, int ldin, bf16* __restrict__ out, int ldout,
    int n0, int k0, int tid)
{
  __shared__ float t[64][65];
  const int cx = (tid & 15) * 4, ry = tid >> 4;
#pragma unroll
  for (int p = 0; p < 4; ++p) {
    const int k = ry + p * 16;
    const float4 v = *(const float4*)(in + (long)(k0 + k) * ldin + n0 + cx);
    t[k][cx] = v.x; t[k][cx + 1] = v.y; t[k][cx + 2] = v.z; t[k][cx + 3] = v.w;
  }
  __syncthreads();
#pragma unroll
  for (int p = 0; p < 4; ++p) {
    const int n = ry + p * 16;
    ushort4 o;
    o.x = __builtin_bit_cast(ushort, __float2bfloat16(t[cx + 0][n]));
    o.y = __builtin_bit_cast(ushort, __float2bfloat16(t[cx + 1][n]));
    o.z = __builtin_bit_cast(ushort, __float2bfloat16(t[cx + 2][n]));
    o.w = __builtin_bit_cast(ushort, __float2bfloat16(t[cx + 3][n]));
    *(ushort4*)(out + (long)(n0 + n) * ldout + k0 + cx) = o;
  }
}

// ---------------- standalone transpose (Wout) ----------------
__global__ __launch_bounds__(256) void transpose_kernel(
    const float* __restrict__ in, long sInZ, int ldin,
    bf16* __restrict__ out, long sOutZ, int ldout)
{
  transpose_tile(in + (long)blockIdx.z * sInZ, ldin,
                 out + (long)blockIdx.z * sOutZ, ldout,
                 blockIdx.x * 64, blockIdx.y * 64, threadIdx.x);
}

// ---------------- fused ATTENTION weight prep -> wqvT [H][896][D] ----------------
// ORDER CONSTRAINT (r16 bug): w1T/w2T alias wqvT; FF prep after QKV GEMM+vmeanw.
__global__ __launch_bounds__(256) void prep_attn_kernel(
    const float* __restrict__ Wq_l, const float* __restrict__ Wk_l,
    const float* __restrict__ Wv_l,
    const float* __restrict__ bq_l, const float* __restrict__ bk_l,
    bf16* __restrict__ wqvT, float* __restrict__ biasqk)
{
  const int tid = threadIdx.x;
  int f = blockIdx.x;
  if (f < 144) {
    const int h = f / 12, ky = f % 12;
    transpose_tile(Wq_l + (long)h * DM * KDH, KDH,
                   wqvT + (long)h * 896 * DM, DM, 0, ky * 64, tid);
  } else if (f < 288) {
    f -= 144;
    const int h = f / 12, ky = f % 12;
    transpose_tile(Wk_l + (long)h * DM * KDH, KDH,
                   wqvT + (long)h * 896 * DM + (long)64 * DM, DM, 0, ky * 64, tid);
  } else if (f < 2016) {
    f -= 288;
    const int h = f / 144, r = f % 144;
    transpose_tile(Wv_l + (long)h * DM * DM, DM,
                   wqvT + (long)h * 896 * DM + (long)128 * DM, DM,
                   (r % 12) * 64, (r / 12) * 64, tid);
  } else {
    const int i = (f - 2016) * 256 + tid;
    if (i < NH * 128) {
      const int h = i >> 7, n = i & 127;
      biasqk[i] = (n < 64) ? bq_l[h * 64 + n] : bk_l[h * 64 + n - 64];
    }
  }
}

// ---------------- fused FF weight prep ----------------
__global__ __launch_bounds__(256) void prep_ff_kernel(
    const float* __restrict__ W1_l, const float* __restrict__ W2_l,
    bf16* __restrict__ w1T, bf16* __restrict__ w2T)
{
  const int tid = threadIdx.x;
  int f = blockIdx.x;
  if (f < 576) {
    transpose_tile(W1_l, FFD, w1T, DM, (f % 48) * 64, (f / 48) * 64, tid);
  } else {
    f -= 576;
    transpose_tile(W2_l, DM, w2T, FFD, (f % 12) * 64, (f / 12) * 64, tid);
  }
}

// ---------------- xmean pipeline (analytic pad-row attention) ----------------
__global__ __launch_bounds__(256) void xpart_kernel(
    const float* __restrict__ x, float* __restrict__ xpart) {
  const int b = blockIdx.x, g = blockIdx.y;
  const int tid = threadIdx.x;
  const float* xp = x + (long)b * SQ * DM + (long)g * 64 * DM;
  float a0 = 0.f, a1 = 0.f, a2 = 0.f;
  for (int s = 0; s < 64; ++s) {
    a0 += xp[(long)s * DM + tid];
    a1 += xp[(long)s * DM + tid + 256];
    a2 += xp[(long)s * DM + tid + 512];
  }
  float* op = xpart + (long)(b * 16 + g) * DM;
  op[tid] = a0; op[tid + 256] = a1; op[tid + 512] = a2;
}

// vmean[b][e] = (1/H) * sum_h ( dot(xmean[b,:], wqvT[h,128+e,:]) + bv[h,e] )
__global__ __launch_bounds__(256) void vmeanw_kernel(
    const float* __restrict__ xpart, const bf16* __restrict__ wqvT,
    const float* __restrict__ bv, float* __restrict__ vmean) {
  const int tid = threadIdx.x;
  const int w = blockIdx.x * 4 + (tid >> 6);
  const int b = w / DM;
  const int e = w % DM;
  const int lane = tid & 63;
  float xm[12];
#pragma unroll
  for (int j = 0; j < 12; ++j) {
    float a = 0.f;
#pragma unroll
    for (int g = 0; g < 16; ++g)
      a += xpart[(long)(b * 16 + g) * DM + lane + j * 64];
    xm[j] = a * (1.0f / (float)SQ);
  }
  float acc = 0.f;
  for (int h = 0; h < NH; ++h) {
    const bf16* wr = wqvT + ((long)h * 896 + 128 + e) * DM;
#pragma unroll
    for (int j = 0; j < 12; ++j)
      acc += xm[j] * __bfloat162float(wr[lane + j * 64]);
  }
#pragma unroll
  for (int o = 32; o >= 1; o >>= 1) acc += __shfl_xor(acc, o);
  if (lane == 0) {
    float bs = 0.f;
#pragma unroll
    for (int h = 0; h < NH; ++h) bs += bv[h * DM + e];
    vmean[b * DM + e] = (acc + bs) * (1.0f / (float)NH);
  }
}

// ---------------- embedding + PE -> x fp32 + xb bf16 ----------------
__global__ __launch_bounds__(256) void embed_kernel(
    const int* __restrict__ tok, const float* __restrict__ emb,
    float* __restrict__ x, bf16* __restrict__ xb)
{
  const int gid = blockIdx.x * 256 + threadIdx.x;
  const int row = gid / (DM / 4);
  const int dc  = (gid % (DM / 4)) * 4;
  const int t = tok[row];
  const int s = row & (SQ - 1);
#pragma unroll
  for (int j = 0; j < 4; ++j) {
    const int d = dc + j;
    const float e = emb[(long)t * DM + d];
    const float div = expf(-(float)(d & ~1) * (9.210340371976184f / (float)DM));
    const float ang = (float)s * div;
    const float pe = (d & 1) ? cosf(ang) : sinf(ang);
    const float v = e + pe;
    x[(long)row * DM + d] = v;
    xb[(long)row * DM + d] = __float2bfloat16(v);
  }
}

// ---------------- masked softmax, causal-truncated (write range (s|127)+1) ----------------
__global__ __launch_bounds__(256) void softmax_kernel(
    bf16* __restrict__ P, const int* __restrict__ tok)
{
  const int row = blockIdx.x;
  const int s = row & (SQ - 1);
  const int z = row >> 10;
  const int b = z / NH;
  const int* tb = tok + b * SQ;
  if (tb[s] == 0) return;
  bf16* sp = P + (long)row * SQ;
  const int tid = threadIdx.x;
  const int t0 = tid * 4;
  const int L = (s | 127) + 1;
  const bool act = t0 < L;

  float val[4] = {-1e30f, -1e30f, -1e30f, -1e30f};
  float vmax = -1e30f;
  if (act) {
    uint2 raw = *(const uint2*)(sp + t0);
    int4 tv = *(const int4*)(tb + t0);
    const bf16* rh = (const bf16*)&raw;
    const int tvv[4] = {tv.x, tv.y, tv.z, tv.w};
#pragma unroll
    for (int j = 0; j < 4; ++j) {
      const int t = t0 + j;
      const bool valid = (t <= s) && (tvv[j] != 0);
      val[j] = valid ? __bfloat162float(rh[j]) * 0.125f : -1e30f;
      vmax = fmaxf(vmax, val[j]);
    }
  }
  __shared__ float red[4];
  const int lane = tid & 63, wid = tid >> 6;
  float w = vmax;
#pragma unroll
  for (int o = 32; o >= 1; o >>= 1) w = fmaxf(w, __shfl_xor(w, o));
  if (lane == 0) red[wid] = w;
  __syncthreads();
  const float Mx = fmaxf(fmaxf(red[0], red[1]), fmaxf(red[2], red[3]));
  __syncthreads();
  float e[4]; float lsum = 0.f;
#pragma unroll
  for (int j = 0; j < 4; ++j) {
    e[j] = (val[j] > -1e29f) ? expf(val[j] - Mx) : 0.f;
    lsum += e[j];
  }
  w = lsum;
#pragma unroll
  for (int o = 32; o >= 1; o >>= 1) w += __shfl_xor(w, o);
  if (lane == 0) red[wid] = w;
  __syncthreads();
  const float inv = 1.0f / (red[0] + red[1] + red[2] + red[3]);
  if (act) {
    ushort4 pk;
    pk.x = __builtin_bit_cast(ushort, __float2bfloat16(e[0] * inv));
    pk.y = __builtin_bit_cast(ushort, __float2bfloat16(e[1] * inv));
    pk.z = __builtin_bit_cast(ushort, __float2bfloat16(e[2] * inv));
    pk.w = __builtin_bit_cast(ushort, __float2bfloat16(e[3] * inv));
    *(ushort4*)(sp + t0) = pk;
  }
}

// ---------------- residual + LayerNorm, vectorized ----------------
#define TCHUNK 1572864L
template<int MODE>
__global__ __launch_bounds__(256) void ln_kernel(
    float* __restrict__ x, bf16* __restrict__ xb,
    const float* __restrict__ tmp, const bf16* __restrict__ heads,
    const float* __restrict__ g, const float* __restrict__ be,
    const int* __restrict__ tok, const float* __restrict__ vmean,
    const float* __restrict__ bias)
{
  const int r = blockIdx.x;
  const int b = r >> 10;
  const int s = r & (SQ - 1);
  const int tid = threadIdx.x;
  __shared__ float rs[4], rq[4];
  const bool pad = (MODE == 1) && (tok[r] == 0);
  float sum = 0.f, sq = 0.f;
  float v[8];
  if (tid < 96) {
    const int d0 = tid * 8;
    const float4 x0 = *(const float4*)(x + (long)r * DM + d0);
    const float4 x1 = *(const float4*)(x + (long)r * DM + d0 + 4);
    v[0] = x0.x; v[1] = x0.y; v[2] = x0.z; v[3] = x0.w;
    v[4] = x1.x; v[5] = x1.y; v[6] = x1.z; v[7] = x1.w;
    if (MODE == 0) {
#pragma unroll
      for (int c = 0; c < 4; ++c) {
        const float* tp = tmp + c * TCHUNK + (long)r * DM + d0;
        const float4 t0_ = *(const float4*)tp;
        const float4 t1_ = *(const float4*)(tp + 4);
        v[0] += t0_.x; v[1] += t0_.y; v[2] += t0_.z; v[3] += t0_.w;
        v[4] += t1_.x; v[5] += t1_.y; v[6] += t1_.z; v[7] += t1_.w;
      }
      const float4 b0_ = *(const float4*)(bias + d0);
      const float4 b1_ = *(const float4*)(bias + d0 + 4);
      v[0] += b0_.x; v[1] += b0_.y; v[2] += b0_.z; v[3] += b0_.w;
      v[4] += b1_.x; v[5] += b1_.y; v[6] += b1_.z; v[7] += b1_.w;
    } else if (pad) {
      const float4 t0_ = *(const float4*)(vmean + b * DM + d0);
      const float4 t1_ = *(const float4*)(vmean + b * DM + d0 + 4);
      v[0] += t0_.x; v[1] += t0_.y; v[2] += t0_.z; v[3] += t0_.w;
      v[4] += t1_.x; v[5] += t1_.y; v[6] += t1_.z; v[7] += t1_.w;
    } else {
      float hs[8] = {0.f, 0.f, 0.f, 0.f, 0.f, 0.f, 0.f, 0.f};
      for (int h = 0; h < NH; ++h) {
        union { uint4 u; ushort us[8]; } hv;
        hv.u = *(const uint4*)(heads + ((long)(b * NH + h) * SQ + s) * DM + d0);
#pragma unroll
        for (int j = 0; j < 8; ++j)
          hs[j] += __bfloat162float(__builtin_bit_cast(bf16, hv.us[j]));
      }
#pragma unroll
      for (int j = 0; j < 8; ++j) v[j] += hs[j] * (1.0f / (float)NH);
    }
#pragma unroll
    for (int j = 0; j < 8; ++j) { sum += v[j]; sq += v[j] * v[j]; }
  }
  const int lane = tid & 63, wid = tid >> 6;
  float s1 = sum, s2 = sq;
#pragma unroll
  for (int o = 32; o >= 1; o >>= 1) { s1 += __shfl_xor(s1, o); s2 += __shfl_xor(s2, o); }
  if (lane == 0) { rs[wid] = s1; rq[wid] = s2; }
  __syncthreads();
  const float S1 = rs[0] + rs[1] + rs[2] + rs[3];
  const float S2 = rq[0] + rq[1] + rq[2] + rq[3];
  const float mean = S1 * (1.0f / (float)DM);
  const float var  = S2 * (1.0f / (float)DM) - mean * mean;
  const float rstd = rsqrtf(var + 1e-5f);
  if (tid < 96) {
    const int d0 = tid * 8;
    const float4 g0 = *(const float4*)(g + d0);
    const float4 g1 = *(const float4*)(g + d0 + 4);
    const float4 b0 = *(const float4*)(be + d0);
    const float4 b1 = *(const float4*)(be + d0 + 4);
    float o[8];
    o[0] = (v[0] - mean) * rstd * g0.x + b0.x;
    o[1] = (v[1] - mean) * rstd * g0.y + b0.y;
    o[2] = (v[2] - mean) * rstd * g0.z + b0.z;
    o[3] = (v[3] - mean) * rstd * g0.w + b0.w;
    o[4] = (v[4] - mean) * rstd * g1.x + b1.x;
    o[5] = (v[5] - mean) * rstd * g1.y + b1.y;
    o[6] = (v[6] - mean) * rstd * g1.z + b1.z;
    o[7] = (v[7] - mean) * rstd * g1.w + b1.w;
    *(float4*)(x + (long)r * DM + d0)     = make_float4(o[0], o[1], o[2], o[3]);
    *(float4*)(x + (long)r * DM + d0 + 4) = make_float4(o[4], o[5], o[6], o[7]);
    union { uint4 u; ushort us[8]; } pk;
#pragma unroll
    for (int j = 0; j < 8; ++j)
      pk.us[j] = __builtin_bit_cast(ushort, __float2bfloat16(o[j]));
    *(uint4*)(xb + (long)r * DM + d0) = pk.u;
  }
}

extern "C" void kernel_launch(void* const* d_in, const int* in_sizes, int n_in,
                              void* d_out, int out_size, void* d_ws, size_t ws_size,
                              hipStream_t stream) {
  const int expect_sizes[18] = {
    2048, 24576000, 3538944, 4608, 3538944, 4608, 42467328, 55296,
    4608, 4608, 4608, 4608, 14155776, 18432, 14155776, 4608, 24576000, 32000
  };
  bool sizes_ok = (n_in == 18);
  if (sizes_ok)
    for (int i = 0; i < 18; ++i) sizes_ok = sizes_ok && (in_sizes[i] == expect_sizes[i]);
  if (!sizes_ok) {
    fill_kernel<<<2048, 256, 0, stream>>>((float*)d_out, (long)out_size, 1000.0f);
    return;
  }
  if (out_size != 65536000) {
    fill_kernel<<<2048, 256, 0, stream>>>((float*)d_out, (long)out_size, 3000.0f);
    return;
  }
  if (ws_size < 158189568ull) {
    fill_kernel<<<2048, 256, 0, stream>>>((float*)d_out, (long)out_size, 2000.0f);
    return;
  }

  // raise dynamic-LDS cap for the 256-row logits kernel
  (void)hipFuncSetAttribute((const void*)&gemm256,
      hipFuncAttributeMaxDynamicSharedMemorySize, 73728);

  const int*   tok  = (const int*)d_in[0];
  const float* emb  = (const float*)d_in[1];
  const float* Wq   = (const float*)d_in[2];
  const float* bq   = (const float*)d_in[3];
  const float* Wk   = (const float*)d_in[4];
  const float* bk   = (const float*)d_in[5];
  const float* Wv   = (const float*)d_in[6];
  const float* bv   = (const float*)d_in[7];
  const float* g1   = (const float*)d_in[8];
  const float* be1  = (const float*)d_in[9];
  const float* g2   = (const float*)d_in[10];
  const float* be2  = (const float*)d_in[11];
  const float* W1   = (const float*)d_in[12];
  const float* b1   = (const float*)d_in[13];
  const float* W2   = (const float*)d_in[14];
  const float* b2   = (const float*)d_in[15];
  const float* Wout = (const float*)d_in[16];
  const float* bout = (const float*)d_in[17];

  char* ws = (char*)d_ws;
  float* x      = (float*)(ws + 0);
  bf16*  xb     = (bf16*) (ws + 6291456);
  bf16*  qk     = (bf16*) (ws + 9437184);
  bf16*  vT     = (bf16*) (ws + 15728640);
  float* tmp    = (float*)(ws + 15728640);
  bf16*  P      = (bf16*) (ws + 53477376);
  bf16*  woutT  = (bf16*) (ws + 53477376);
  bf16*  heads  = (bf16*) (ws + 103809024);
  bf16*  wqvT   = (bf16*) (ws + 141557760);    // [H][896][D] bf16
  bf16*  w1T    = (bf16*) (ws + 141557760);    // FF phase (aliases wqvT)
  bf16*  w2T    = (bf16*) (ws + 146276352);
  float* biasqk = (float*)(ws + 158072832);
  float* xpart  = (float*)(ws + 158078976);
  float* vmean  = (float*)(ws + 158183424);

  embed_kernel<<<dim3((2 * SQ * DM / 4) / 256), 256, 0, stream>>>(tok, emb, x, xb);

  for (int l = 0; l < NL; ++l) {
    prep_attn_kernel<<<dim3(2022), 256, 0, stream>>>(
        Wq + (long)l * NH * DM * KDH, Wk + (long)l * NH * DM * KDH,
        Wv + (long)l * NH * DM * DM,
        bq + l * NH * KDH, bk + l * NH * KDH,
        wqvT, biasqk);

    xpart_kernel<<<dim3(2, 16), 256, 0, stream>>>(x, xpart);
    vmeanw_kernel<<<dim3(384), 256, 0, stream>>>(xpart, wqvT, bv + (long)l * NH * DM, vmean);

    // fused Q|K|V projection (128-row tile)
    gemm_bt<true, false, false, false, true><<<dim3(16, 7, NH), 256, 0, stream>>>(
        2048, 896, DM, xb, 0, DM, wqvT, (long)896 * DM, DM,
        biasqk, 128,
        qk, 0, 0, 0, 0,
        vT, bv + (long)l * NH * DM);
    // scores = Q @ K^T -> P  (compact triangular grid)
    gemm_bt<true, false, true, false><<<dim3(36, 1, 2 * NH), 256, 0, stream>>>(
        SQ, SQ, KDH, qk, (long)SQ * 128, 128, qk + 64, (long)SQ * 128, 128,
        (const float*)nullptr, 0,
        P, (long)SQ * SQ, 0, SQ, 1);
    softmax_kernel<<<dim3(2 * NH * SQ), 256, 0, stream>>>(P, tok);
    // heads = P @ V (causal K-truncation)
    gemm_bt<true, false, false, true><<<dim3(8, 6, 2 * NH), 256, 0, stream>>>(
        SQ, DM, SQ, P, (long)SQ * SQ, SQ, vT, (long)DM * SQ, SQ,
        (const float*)nullptr, 0,
        heads, (long)SQ * DM, 0, DM, 1);
    ln_kernel<1><<<dim3(2048), 256, 0, stream>>>(x, xb, nullptr, heads,
                                                 g1 + l * DM, be1 + l * DM, tok, vmean,
                                                 nullptr);
    prep_ff_kernel<<<dim3(1152), 256, 0, stream>>>(
        W1 + (long)l * DM * FFD, W2 + (long)l * FFD * DM, w1T, w2T);
    gemm_bt<true, true><<<dim3(16, 24, 1), 256, 0, stream>>>(
        2048, FFD, DM, xb, 0, DM, w1T, 0, DM,
        b1 + (long)l * FFD, 0,
        (bf16*)P, 0, (long)SQ * FFD, FFD, 1);
    gemm_bt<false, false><<<dim3(16, 6, 4), 256, 0, stream>>>(
        2048, DM, 768, (bf16*)P, 768, FFD, w2T, 768, FFD,
        (const float*)nullptr, 0,
        tmp, TCHUNK, (long)SQ * DM, DM, 1);
    ln_kernel<0><<<dim3(2048), 256, 0, stream>>>(x, xb, tmp, nullptr,
                                                 g2 + l * DM, be2 + l * DM, tok, nullptr,
                                                 b2 + (long)l * DM);
  }
  transpose_kernel<<<dim3(500, 12, 1), 256, 0, stream>>>(Wout, 0, NV, woutT, 0, DM);
  // logits: 256-row kernel (big grid: 2000 blocks of 512 thr — r21's win)
  gemm256<<<dim3(8, 250), 512, 73728, stream>>>(
      2048, NV, DM, xb, DM, woutT, DM, bout, (float*)d_out, NV, 1);
}